// Round 17
// baseline (193.071 us; speedup 1.0000x reference)
//
#include <hip/hip_runtime.h>
#include <hip/hip_bf16.h>
#include <math.h>

// N = 100000, E = 1600000, F_IN = H = 128, C = 40
typedef __bf16 bf16x8 __attribute__((ext_vector_type(8)));
typedef float f32x4 __attribute__((ext_vector_type(4)));
typedef float f32x2 __attribute__((ext_vector_type(2)));
typedef unsigned int uint32;

#define CHUNK 4096        // edges per chunk in the bin-sort passes
#define MAXBINS 512       // LDS histogram capacity (nBins = ceil(N/256) = 391)

__device__ __forceinline__ float bflo(uint32 u) { return __uint_as_float(u << 16); }
__device__ __forceinline__ float bfhi(uint32 u) { return __uint_as_float(u & 0xffff0000u); }
__device__ __forceinline__ unsigned short tobf(float f) {
    return __builtin_bit_cast(unsigned short, __float2bfloat16(f));
}
__device__ __forceinline__ unsigned char tofp8(float f) {
    return (unsigned char)(__builtin_amdgcn_cvt_pk_fp8_f32(f, f, 0, false) & 0xff);
}

// ---------------- CSR build: 2-level LDS counting sort (no global atomics) ----------------

__global__ __launch_bounds__(256) void binhist_kernel(
    const int* __restrict__ dst, int* __restrict__ blkhist,
    int nE, int nChunks, int nBins)
{
    __shared__ int h[MAXBINS];
    int blk = blockIdx.x, t = threadIdx.x;
    for (int i = t; i < nBins; i += 256) h[i] = 0;
    __syncthreads();
    int e0 = blk * CHUNK;
    int e1 = e0 + CHUNK; if (e1 > nE) e1 = nE;
    for (int e = e0 + t; e < e1; e += 256)
        atomicAdd(&h[dst[e] >> 8], 1);      // LDS atomic
    __syncthreads();
    for (int b = t; b < nBins; b += 256)
        blkhist[(size_t)b * nChunks + blk] = h[b];
}

__global__ __launch_bounds__(256) void csr_partial_kernel(
    const int* __restrict__ cnt, int* __restrict__ blocksum, int nN)
{
    int b = blockIdx.x, t = threadIdx.x;
    int base = b * 1024 + t * 4;
    int s = 0;
    #pragma unroll
    for (int k = 0; k < 4; ++k) { int i = base + k; if (i < nN) s += cnt[i]; }
    #pragma unroll
    for (int off = 1; off < 64; off <<= 1) s += __shfl_xor(s, off);
    __shared__ int ws[4];
    int lane = t & 63, w = t >> 6;
    if (lane == 0) ws[w] = s;
    __syncthreads();
    if (t == 0) blocksum[b] = ws[0] + ws[1] + ws[2] + ws[3];
}

__global__ __launch_bounds__(1024) void csr_scanblocks_kernel(
    const int* __restrict__ blocksum, int* __restrict__ blockpre,
    int nB, int* __restrict__ outtot, int nN)
{
    __shared__ int sm[1024];
    int t = threadIdx.x;
    int v = (t < nB) ? blocksum[t] : 0;
    sm[t] = v;
    __syncthreads();
    for (int off = 1; off < 1024; off <<= 1) {
        int u = (t >= off) ? sm[t - off] : 0;
        __syncthreads();
        sm[t] += u;
        __syncthreads();
    }
    if (t < nB) blockpre[t] = sm[t] - v;
    if (t == 1023) outtot[nN] = sm[1023];
}

__global__ __launch_bounds__(256) void csr_scanfinal_kernel(
    const int* __restrict__ cnt, const int* __restrict__ blockpre,
    int* __restrict__ out, int nN)
{
    int b = blockIdx.x, t = threadIdx.x;
    int base = b * 1024 + t * 4;
    int c[4]; int s = 0;
    #pragma unroll
    for (int k = 0; k < 4; ++k) { int i = base + k; c[k] = (i < nN) ? cnt[i] : 0; s += c[k]; }
    int lane = t & 63, w = t >> 6;
    int inc = s;
    #pragma unroll
    for (int off = 1; off < 64; off <<= 1) {
        int u = __shfl_up(inc, off);
        if (lane >= off) inc += u;
    }
    __shared__ int ws[4];
    if (lane == 63) ws[w] = inc;
    __syncthreads();
    int wpre = 0;
    for (int i = 0; i < w; ++i) wpre += ws[i];
    int run = blockpre[b] + wpre + (inc - s);
    #pragma unroll
    for (int k = 0; k < 4; ++k) {
        int i = base + k;
        if (i < nN) { out[i] = run; run += c[k]; }
    }
}

__global__ __launch_bounds__(256) void binscatter_kernel(
    const int* __restrict__ src, const int* __restrict__ dst,
    const int* __restrict__ blkbase, uint32* __restrict__ packed,
    int nE, int nChunks, int nBins)
{
    __shared__ int h[MAXBINS];
    int blk = blockIdx.x, t = threadIdx.x;
    for (int i = t; i < nBins; i += 256) h[i] = 0;
    __syncthreads();
    int e0 = blk * CHUNK;
    int e1 = e0 + CHUNK; if (e1 > nE) e1 = nE;
    for (int e = e0 + t; e < e1; e += 256) {
        int d = dst[e];
        int b = d >> 8;
        int r = atomicAdd(&h[b], 1);        // LDS atomic rank
        int pos = blkbase[(size_t)b * nChunks + blk] + r;
        packed[pos] = (uint32)src[e] | ((uint32)(d & 255) << 24);
    }
}

__global__ __launch_bounds__(256) void binsort_kernel(
    const uint32* __restrict__ packed, const int* __restrict__ blkbase,
    int* __restrict__ rowptr, int* __restrict__ sorted_src,
    int nChunks, int nBins, int nN, int nE)
{
    __shared__ int h[256];
    __shared__ int offs[256];
    __shared__ int ws[4];
    int b = blockIdx.x, t = threadIdx.x;
    int segbase = blkbase[(size_t)b * nChunks];
    int segend  = (b + 1 < nBins) ? blkbase[(size_t)(b + 1) * nChunks] : nE;

    h[t] = 0;
    __syncthreads();
    for (int i = segbase + t; i < segend; i += 256)
        atomicAdd(&h[packed[i] >> 24], 1);
    __syncthreads();

    int c = h[t];
    int lane = t & 63, w = t >> 6;
    int inc = c;
    #pragma unroll
    for (int off = 1; off < 64; off <<= 1) {
        int u = __shfl_up(inc, off);
        if (lane >= off) inc += u;
    }
    if (lane == 63) ws[w] = inc;
    __syncthreads();
    int wpre = 0;
    for (int i = 0; i < w; ++i) wpre += ws[i];
    int ex = wpre + inc - c;
    offs[t] = ex;
    int node = b * 256 + t;
    if (node < nN) rowptr[node] = segbase + ex;
    if (b == 0 && t == 0) rowptr[nN] = nE;
    __syncthreads();

    for (int i = segbase + t; i < segend; i += 256) {
        uint32 pk = packed[i];
        int ld = (int)(pk >> 24);
        int r = atomicAdd(&offs[ld], 1);    // LDS atomic rank
        sorted_src[segbase + r] = (int)(pk & 0x00FFFFFFu);
    }
}

// ---------------- conversions (fused: x->fp8 + weight prep) ----------------
__global__ __launch_bounds__(256) void prep_all_kernel(
    const float4* __restrict__ xin, uint32* __restrict__ xf8out, int n4,
    const float* __restrict__ W1_rel, const float* __restrict__ W1_root,
    const float* __restrict__ W2_rel, const float* __restrict__ W2_root,
    unsigned short* __restrict__ W1relB, unsigned short* __restrict__ W1rootB,
    unsigned short* __restrict__ Wpq)
{
    if (blockIdx.x < 168) {
        int i = blockIdx.x * 256 + threadIdx.x;
        if (i < 16384) {
            W1relB[i] = tobf(W1_rel[i]);
        } else if (i < 32768) {
            int j = i - 16384;
            W1rootB[j] = tobf(W1_root[j]);
        } else if (i < 32768 + 10240) {
            int j = i - 32768;
            int o = j >> 7, k = j & 127;
            float v = (o < 40) ? W2_rel[o * 128 + k] : W2_root[(o - 40) * 128 + k];
            Wpq[j] = tobf(v);
        }
    } else {
        int i = (blockIdx.x - 168) * 256 + threadIdx.x;
        int stride = (gridDim.x - 168) * 256;
        for (; i < n4; i += stride) {
            float4 v = xin[i];
            int w = __builtin_amdgcn_cvt_pk_fp8_f32(v.x, v.y, 0, false);
            w = __builtin_amdgcn_cvt_pk_fp8_f32(v.z, v.w, w, true);
            xf8out[i] = (uint32)w;
        }
    }
}

// ---------------- layer-1 gather (fp8 in, bf16 out, f32 accum) ----------------
// wave = 1 node; BLOCKED half-wave split (half h owns 8 consecutive edges),
// indices via int2 loads (j kept even by head peel); flat predicated tail.
__global__ __launch_bounds__(256) void aggregate_fp8_kernel(
    const uint32* __restrict__ xf8u,      // [N][32] uints (128 fp8/row)
    const int* __restrict__ rowptr,
    const int* __restrict__ sorted_src,
    uint2* __restrict__ aggout2,          // [N][32] uint2 (128 bf16/row)
    int nN)
{
    int wave = threadIdx.x >> 6;
    int lane = threadIdx.x & 63;
    int node = blockIdx.x * 4 + wave;
    if (node >= nN) return;
    int half = lane >> 5, l32 = lane & 31;
    int beg = rowptr[node], end = rowptr[node + 1];
    float a0 = 0.f, a1 = 0.f, a2 = 0.f, a3 = 0.f;
    int j = beg;
    // head peel: make j even (enables aligned int2 index loads)
    if ((j & 1) && j < end) {
        if (half == 0) {
            uint32 u = xf8u[(size_t)sorted_src[j] * 32 + l32];
            f32x2 p = __builtin_amdgcn_cvt_pk_f32_fp8(u, false);
            f32x2 q = __builtin_amdgcn_cvt_pk_f32_fp8(u, true);
            a0 += p[0]; a1 += p[1]; a2 += q[0]; a3 += q[1];
        }
        ++j;
    }
    for (; j + 16 <= end; j += 16) {
        int base = j + 8 * half;               // even -> 8B-aligned int2 loads
        int2 i01 = *(const int2*)(sorted_src + base);
        int2 i23 = *(const int2*)(sorted_src + base + 2);
        int2 i45 = *(const int2*)(sorted_src + base + 4);
        int2 i67 = *(const int2*)(sorted_src + base + 6);
        uint32 u0 = xf8u[(size_t)i01.x * 32 + l32];
        uint32 u1 = xf8u[(size_t)i01.y * 32 + l32];
        uint32 u2 = xf8u[(size_t)i23.x * 32 + l32];
        uint32 u3 = xf8u[(size_t)i23.y * 32 + l32];
        uint32 u4 = xf8u[(size_t)i45.x * 32 + l32];
        uint32 u5 = xf8u[(size_t)i45.y * 32 + l32];
        uint32 u6 = xf8u[(size_t)i67.x * 32 + l32];
        uint32 u7 = xf8u[(size_t)i67.y * 32 + l32];
        f32x2 p0 = __builtin_amdgcn_cvt_pk_f32_fp8(u0, false);
        f32x2 q0 = __builtin_amdgcn_cvt_pk_f32_fp8(u0, true);
        f32x2 p1 = __builtin_amdgcn_cvt_pk_f32_fp8(u1, false);
        f32x2 q1 = __builtin_amdgcn_cvt_pk_f32_fp8(u1, true);
        f32x2 p2 = __builtin_amdgcn_cvt_pk_f32_fp8(u2, false);
        f32x2 q2 = __builtin_amdgcn_cvt_pk_f32_fp8(u2, true);
        f32x2 p3 = __builtin_amdgcn_cvt_pk_f32_fp8(u3, false);
        f32x2 q3 = __builtin_amdgcn_cvt_pk_f32_fp8(u3, true);
        f32x2 p4 = __builtin_amdgcn_cvt_pk_f32_fp8(u4, false);
        f32x2 q4 = __builtin_amdgcn_cvt_pk_f32_fp8(u4, true);
        f32x2 p5 = __builtin_amdgcn_cvt_pk_f32_fp8(u5, false);
        f32x2 q5 = __builtin_amdgcn_cvt_pk_f32_fp8(u5, true);
        f32x2 p6 = __builtin_amdgcn_cvt_pk_f32_fp8(u6, false);
        f32x2 q6 = __builtin_amdgcn_cvt_pk_f32_fp8(u6, true);
        f32x2 p7 = __builtin_amdgcn_cvt_pk_f32_fp8(u7, false);
        f32x2 q7 = __builtin_amdgcn_cvt_pk_f32_fp8(u7, true);
        a0 += ((p0[0] + p1[0]) + (p2[0] + p3[0])) + ((p4[0] + p5[0]) + (p6[0] + p7[0]));
        a1 += ((p0[1] + p1[1]) + (p2[1] + p3[1])) + ((p4[1] + p5[1]) + (p6[1] + p7[1]));
        a2 += ((q0[0] + q1[0]) + (q2[0] + q3[0])) + ((q4[0] + q5[0]) + (q6[0] + q7[0]));
        a3 += ((q0[1] + q1[1]) + (q2[1] + q3[1])) + ((q4[1] + q5[1]) + (q6[1] + q7[1]));
    }
    // flat predicated tail: remainder < 16 edges, one parallel load round
    {
        uint32 u[8] = {0, 0, 0, 0, 0, 0, 0, 0};
        #pragma unroll
        for (int k = 0; k < 8; ++k) {
            int e = j + 2 * k + half;
            if (e < end) u[k] = xf8u[(size_t)sorted_src[e] * 32 + l32];
        }
        #pragma unroll
        for (int k = 0; k < 8; ++k) {
            f32x2 p = __builtin_amdgcn_cvt_pk_f32_fp8(u[k], false);
            f32x2 q = __builtin_amdgcn_cvt_pk_f32_fp8(u[k], true);
            a0 += p[0]; a1 += p[1]; a2 += q[0]; a3 += q[1];
        }
    }
    a0 += __shfl_xor(a0, 32);
    a1 += __shfl_xor(a1, 32);
    a2 += __shfl_xor(a2, 32);
    a3 += __shfl_xor(a3, 32);
    if (half == 0) {
        uint2 o;
        o.x = (uint32)tobf(a0) | ((uint32)tobf(a1) << 16);
        o.y = (uint32)tobf(a2) | ((uint32)tobf(a3) << 16);
        aggout2[(size_t)node * 32 + l32] = o;
    }
}

// ---------------- fused: h = relu([agg|x]@W1^T + b1); pq = h @ Wpq^T ----------------
__global__ __launch_bounds__(256) void gemm_fused_kernel(
    const unsigned short* __restrict__ aggb,
    const float* __restrict__ xf,
    const unsigned short* __restrict__ Wrel,
    const unsigned short* __restrict__ Wroot,
    const unsigned short* __restrict__ Wpq,    // [80][128]
    const float* __restrict__ b1,
    unsigned char* __restrict__ pf8,           // [N][40] fp8 (+pad)
    unsigned short* __restrict__ qb,           // [N][40] bf16
    int nN)
{
    __shared__ __align__(16) unsigned char lds[32768];    // weight staging
    __shared__ __align__(16) unsigned char hlds[16384];   // h tile 64x128 bf16 (swizzled)
    int tid = threadIdx.x;
    int wave = tid >> 6, lane = tid & 63;
    int i0 = blockIdx.x * 64 + wave * 16;
    int mrow = lane & 15, kslot = lane >> 4;
    int arow = i0 + mrow; if (arow >= nN) arow = 0;

    f32x4 acc[8] = {};
    const unsigned short* Wsrc[2] = {Wrel, Wroot};

    for (int ph = 0; ph < 2; ++ph) {
        __syncthreads();
        const uint4* src = (const uint4*)Wsrc[ph];
        for (int c = tid; c < 2048; c += 256) {
            int row = c >> 4;
            int off = (c & 15) << 4;
            *(uint4*)(&lds[row * 256 + (off ^ ((row & 7) << 4))]) = src[c];
        }
        __syncthreads();
        if (ph == 0) {
            const unsigned short* Ap = aggb + (size_t)arow * 128 + kslot * 8;
            #pragma unroll
            for (int t = 0; t < 4; ++t) {
                bf16x8 a = *(const bf16x8*)(Ap + t * 32);
                #pragma unroll
                for (int ct = 0; ct < 8; ++ct) {
                    int o = ct * 16 + mrow;
                    int off = (t * 64 + kslot * 16) ^ ((o & 7) << 4);
                    bf16x8 b = *(const bf16x8*)(&lds[o * 256 + off]);
                    acc[ct] = __builtin_amdgcn_mfma_f32_16x16x32_bf16(a, b, acc[ct], 0, 0, 0);
                }
            }
        } else {
            const float* Ap = xf + (size_t)arow * 128 + kslot * 8;
            #pragma unroll
            for (int t = 0; t < 4; ++t) {
                float4 f0 = *(const float4*)(Ap + t * 32);
                float4 f1 = *(const float4*)(Ap + t * 32 + 4);
                union { bf16x8 v; unsigned short u[8]; } a;
                a.u[0] = tobf(f0.x); a.u[1] = tobf(f0.y);
                a.u[2] = tobf(f0.z); a.u[3] = tobf(f0.w);
                a.u[4] = tobf(f1.x); a.u[5] = tobf(f1.y);
                a.u[6] = tobf(f1.z); a.u[7] = tobf(f1.w);
                #pragma unroll
                for (int ct = 0; ct < 8; ++ct) {
                    int o = ct * 16 + mrow;
                    int off = (t * 64 + kslot * 16) ^ ((o & 7) << 4);
                    bf16x8 b = *(const bf16x8*)(&lds[o * 256 + off]);
                    acc[ct] = __builtin_amdgcn_mfma_f32_16x16x32_bf16(a.v, b, acc[ct], 0, 0, 0);
                }
            }
        }
    }

    // epilogue 1: bias + relu -> swizzled LDS h tile
    #pragma unroll
    for (int ct = 0; ct < 8; ++ct) {
        int col = ct * 16 + mrow;
        float bias = b1[col];
        #pragma unroll
        for (int r = 0; r < 4; ++r) {
            int rl = wave * 16 + kslot * 4 + r;
            float v = fmaxf(acc[ct][r] + bias, 0.f);
            *(unsigned short*)(&hlds[rl * 256 + ((col * 2) ^ ((rl & 7) << 4))]) = tobf(v);
        }
    }
    __syncthreads();

    // stage Wpq (80 rows x 256B)
    {
        const uint4* src = (const uint4*)Wpq;
        for (int c = tid; c < 1280; c += 256) {
            int row = c >> 4;
            int off = (c & 15) << 4;
            *(uint4*)(&lds[row * 256 + (off ^ ((row & 7) << 4))]) = src[c];
        }
    }
    __syncthreads();

    // pass 2: pq = h @ Wpq^T (5 col-tiles of 16 = 80 cols)
    f32x4 acc2[5] = {};
    {
        int rl = wave * 16 + mrow;
        #pragma unroll
        for (int t = 0; t < 4; ++t) {
            bf16x8 a = *(const bf16x8*)(&hlds[rl * 256 + ((t * 64 + kslot * 16) ^ ((rl & 7) << 4))]);
            #pragma unroll
            for (int ct = 0; ct < 5; ++ct) {
                int o = ct * 16 + mrow;
                int off = (t * 64 + kslot * 16) ^ ((o & 7) << 4);
                bf16x8 b = *(const bf16x8*)(&lds[o * 256 + off]);
                acc2[ct] = __builtin_amdgcn_mfma_f32_16x16x32_bf16(a, b, acc2[ct], 0, 0, 0);
            }
        }
    }

    // epilogue 2: p (cols 0..39) -> fp8 @ stride 40, q (cols 40..79) -> bf16 @ stride 40
    #pragma unroll
    for (int ct = 0; ct < 5; ++ct) {
        int col = ct * 16 + mrow;
        #pragma unroll
        for (int r = 0; r < 4; ++r) {
            int row = i0 + kslot * 4 + r;
            if (row < nN) {
                if (col < 40) pf8[(size_t)row * 40 + col] = tofp8(acc2[ct][r]);
                else          qb[(size_t)row * 40 + (col - 40)] = tobf(acc2[ct][r]);
            }
        }
    }
}

// ---------------- final: out = lsm(gather-sum p[neighbors] + q[node] + b2) ----------------
// wave = 1 node; 3 edges per row-load instruction; 9-edge main loop + flat tail.
// Lanes 60..63 idle.
__global__ __launch_bounds__(256) void final_lsm_kernel(
    const unsigned short* __restrict__ pf8u,  // [N] rows of 20 ushorts (40 fp8)
    const uint32* __restrict__ qbu,           // [N] rows of 20 uints (40 bf16)
    const int* __restrict__ rowptr,
    const int* __restrict__ sorted_src,
    const float* __restrict__ b2,
    float* __restrict__ out,
    int nN)
{
    int wave = threadIdx.x >> 6;
    int lane = threadIdx.x & 63;
    int node = blockIdx.x * 4 + wave;
    if (node >= nN) return;

    int esub = (lane >= 40) ? 2 : (lane >= 20 ? 1 : 0);
    int cp   = lane - esub * 20;
    bool active = lane < 60;
    int beg = rowptr[node], end = rowptr[node + 1];

    // hoist independent node-local loads (overlap with gather)
    uint32 uq = 0;
    float2 bb = make_float2(0.f, 0.f);
    if (lane < 20) {
        uq = qbu[(size_t)node * 20 + lane];
        bb = *(const float2*)(b2 + 2 * lane);
    }

    float a0 = 0.f, a1 = 0.f;
    int j = beg;
    if (active) {
        for (; j + 9 <= end; j += 9) {
            int s0 = sorted_src[j + esub];
            int s1 = sorted_src[j + 3 + esub];
            int s2 = sorted_src[j + 6 + esub];
            uint32 u0 = pf8u[(size_t)s0 * 20 + cp];
            uint32 u1 = pf8u[(size_t)s1 * 20 + cp];
            uint32 u2 = pf8u[(size_t)s2 * 20 + cp];
            f32x2 p0 = __builtin_amdgcn_cvt_pk_f32_fp8(u0, false);
            f32x2 p1 = __builtin_amdgcn_cvt_pk_f32_fp8(u1, false);
            f32x2 p2 = __builtin_amdgcn_cvt_pk_f32_fp8(u2, false);
            a0 += (p0[0] + p1[0]) + p2[0];
            a1 += (p0[1] + p1[1]) + p2[1];
        }
        // flat predicated tail: remainder < 9 edges, one parallel load round
        int e0 = j + esub, e1 = j + 3 + esub, e2 = j + 6 + esub;
        uint32 u0 = 0, u1 = 0, u2 = 0;
        if (e0 < end) u0 = pf8u[(size_t)sorted_src[e0] * 20 + cp];
        if (e1 < end) u1 = pf8u[(size_t)sorted_src[e1] * 20 + cp];
        if (e2 < end) u2 = pf8u[(size_t)sorted_src[e2] * 20 + cp];
        f32x2 p0 = __builtin_amdgcn_cvt_pk_f32_fp8(u0, false);
        f32x2 p1 = __builtin_amdgcn_cvt_pk_f32_fp8(u1, false);
        f32x2 p2 = __builtin_amdgcn_cvt_pk_f32_fp8(u2, false);
        a0 += (p0[0] + p1[0]) + p2[0];
        a1 += (p0[1] + p1[1]) + p2[1];
    }
    // combine the 3 edge-groups: lanes cp, cp+20, cp+40 hold the same class pair
    {
        float t0 = __shfl(a0, cp + 20), t1 = __shfl(a0, cp + 40);
        float t2 = __shfl(a1, cp + 20), t3 = __shfl(a1, cp + 40);
        a0 += t0 + t1;
        a1 += t2 + t3;
    }

    float v0, v1;
    if (lane < 20) {
        v0 = a0 + bflo(uq) + bb.x;
        v1 = a1 + bfhi(uq) + bb.y;
    } else {
        v0 = v1 = -INFINITY;
    }

    // 5-round reduces (values live in lanes 0..19)
    float m = fmaxf(v0, v1);
    #pragma unroll
    for (int off = 16; off >= 1; off >>= 1) m = fmaxf(m, __shfl_xor(m, off));
    float s = (lane < 20) ? (expf(v0 - m) + expf(v1 - m)) : 0.f;
    #pragma unroll
    for (int off = 16; off >= 1; off >>= 1) s += __shfl_xor(s, off);
    float lse = m + logf(s);

    if (lane < 20) {
        float2 o = make_float2(v0 - lse, v1 - lse);
        *(float2*)(out + (size_t)node * 40 + 2 * lane) = o;
    }
}

// ---------------- launch ----------------

static inline char* alignup(char* p, size_t a) {
    return (char*)(((uintptr_t)p + a - 1) & ~(uintptr_t)(a - 1));
}

extern "C" void kernel_launch(void* const* d_in, const int* in_sizes, int n_in,
                              void* d_out, int out_size, void* d_ws, size_t ws_size,
                              hipStream_t stream)
{
    const float* x       = (const float*)d_in[0];
    const int*   ei      = (const int*)d_in[1];
    const float* W1_rel  = (const float*)d_in[2];
    const float* b1      = (const float*)d_in[3];
    const float* W1_root = (const float*)d_in[4];
    const float* W2_rel  = (const float*)d_in[5];
    const float* b2      = (const float*)d_in[6];
    const float* W2_root = (const float*)d_in[7];

    int N = in_sizes[0] / 128;
    int E = in_sizes[1] / 2;
    const int* srcp = ei;
    const int* dstp = ei + E;

    int nChunks = (E + CHUNK - 1) / CHUNK;          // 391
    int nBins   = (N + 255) >> 8;                   // 391
    int nScan   = nBins * nChunks;                  // ~153k
    int nB2     = (nScan + 1023) / 1024;
    size_t nf = (size_t)N * 128;

    char* p = (char*)d_ws;
    unsigned char*  xf8     = (unsigned char*)p;   p += nf;            // [N][128] fp8
    unsigned short* aggb    = (unsigned short*)p;  p += nf * 2;        // [N][128] bf16
    p = alignup(p, 16);
    unsigned char*  pf8     = (unsigned char*)p;   p += (size_t)N * 40 + 64; // [N][40] fp8 + pad
    p = alignup(p, 16);
    unsigned short* qb      = (unsigned short*)p;  p += (size_t)N * 40 * 2;  // [N][40] bf16
    p = alignup(p, 16);
    unsigned short* W1relB  = (unsigned short*)p;  p += 16384 * 2;
    unsigned short* W1rootB = (unsigned short*)p;  p += 16384 * 2;
    unsigned short* Wpq     = (unsigned short*)p;  p += 10240 * 2;
    p = alignup(p, 16);
    int* rowptr     = (int*)p;  p += (size_t)(N + 1) * 4;
    p = alignup(p, 16);
    int* blkhist    = (int*)p;  p += (size_t)nScan * 4;
    int* blkbase    = (int*)p;  p += (size_t)(nScan + 1) * 4;
    int* blocksum   = (int*)p;  p += (size_t)nB2 * 4;
    int* blockpre   = (int*)p;  p += (size_t)nB2 * 4;
    p = alignup(p, 16);
    uint32* packed  = (uint32*)p; p += (size_t)E * 4;
    p = alignup(p, 16);
    int* sorted_src = (int*)p;  p += (size_t)E * 4;

    if ((size_t)(p - (char*)d_ws) > ws_size || nBins > MAXBINS) return;

    // CSR build: 2-level counting sort, all atomics in LDS
    binhist_kernel<<<nChunks, 256, 0, stream>>>(dstp, blkhist, E, nChunks, nBins);
    csr_partial_kernel<<<nB2, 256, 0, stream>>>(blkhist, blocksum, nScan);
    csr_scanblocks_kernel<<<1, 1024, 0, stream>>>(blocksum, blockpre, nB2, blkbase, nScan);
    csr_scanfinal_kernel<<<nB2, 256, 0, stream>>>(blkhist, blockpre, blkbase, nScan);
    binscatter_kernel<<<nChunks, 256, 0, stream>>>(srcp, dstp, blkbase, packed, E, nChunks, nBins);
    binsort_kernel<<<nBins, 256, 0, stream>>>(packed, blkbase, rowptr, sorted_src,
                                              nChunks, nBins, N, E);

    // fused conversions: weights (blocks 0..167) + x->fp8 (blocks 168..)
    prep_all_kernel<<<168 + 2048, 256, 0, stream>>>(
        (const float4*)x, (uint32*)xf8, (int)(nf / 4),
        W1_rel, W1_root, W2_rel, W2_root, W1relB, W1rootB, Wpq);

    // layer 1 gather
    aggregate_fp8_kernel<<<(N + 3) / 4, 256, 0, stream>>>(
        (const uint32*)xf8, rowptr, sorted_src, (uint2*)aggb, N);

    // fused layer-1 GEMM + layer-2 pre-transform
    gemm_fused_kernel<<<(N + 63) / 64, 256, 0, stream>>>(
        aggb, x, W1relB, W1rootB, Wpq, b1, pf8, qb, N);

    // fused gather + log-softmax
    final_lsm_kernel<<<(N + 3) / 4, 256, 0, stream>>>(
        (const unsigned short*)pf8, (const uint32*)qb, rowptr, sorted_src,
        b2, (float*)d_out, N);
}

// Round 18
// 187.098 us; speedup vs baseline: 1.0319x; 1.0319x over previous
//
#include <hip/hip_runtime.h>
#include <hip/hip_bf16.h>
#include <math.h>

// N = 100000, E = 1600000, F_IN = H = 128, C = 40
typedef __bf16 bf16x8 __attribute__((ext_vector_type(8)));
typedef float f32x4 __attribute__((ext_vector_type(4)));
typedef float f32x2 __attribute__((ext_vector_type(2)));
typedef unsigned int uint32;

#define CHUNK 4096        // edges per chunk in the bin-sort passes
#define MAXBINS 512       // LDS histogram capacity (nBins = ceil(N/256) = 391)

__device__ __forceinline__ float bflo(uint32 u) { return __uint_as_float(u << 16); }
__device__ __forceinline__ float bfhi(uint32 u) { return __uint_as_float(u & 0xffff0000u); }
__device__ __forceinline__ unsigned short tobf(float f) {
    return __builtin_bit_cast(unsigned short, __float2bfloat16(f));
}
__device__ __forceinline__ unsigned char tofp8(float f) {
    return (unsigned char)(__builtin_amdgcn_cvt_pk_fp8_f32(f, f, 0, false) & 0xff);
}

// ---------------- CSR build: 2-level LDS counting sort (no global atomics) ----------------

__global__ __launch_bounds__(256) void binhist_kernel(
    const int* __restrict__ dst, int* __restrict__ blkhist,
    int nE, int nChunks, int nBins)
{
    __shared__ int h[MAXBINS];
    int blk = blockIdx.x, t = threadIdx.x;
    for (int i = t; i < nBins; i += 256) h[i] = 0;
    __syncthreads();
    int e0 = blk * CHUNK;
    int e1 = e0 + CHUNK; if (e1 > nE) e1 = nE;
    for (int e = e0 + t; e < e1; e += 256)
        atomicAdd(&h[dst[e] >> 8], 1);      // LDS atomic
    __syncthreads();
    for (int b = t; b < nBins; b += 256)
        blkhist[(size_t)b * nChunks + blk] = h[b];
}

__global__ __launch_bounds__(256) void csr_partial_kernel(
    const int* __restrict__ cnt, int* __restrict__ blocksum, int nN)
{
    int b = blockIdx.x, t = threadIdx.x;
    int base = b * 1024 + t * 4;
    int s = 0;
    #pragma unroll
    for (int k = 0; k < 4; ++k) { int i = base + k; if (i < nN) s += cnt[i]; }
    #pragma unroll
    for (int off = 1; off < 64; off <<= 1) s += __shfl_xor(s, off);
    __shared__ int ws[4];
    int lane = t & 63, w = t >> 6;
    if (lane == 0) ws[w] = s;
    __syncthreads();
    if (t == 0) blocksum[b] = ws[0] + ws[1] + ws[2] + ws[3];
}

__global__ __launch_bounds__(1024) void csr_scanblocks_kernel(
    const int* __restrict__ blocksum, int* __restrict__ blockpre,
    int nB, int* __restrict__ outtot, int nN)
{
    __shared__ int sm[1024];
    int t = threadIdx.x;
    int v = (t < nB) ? blocksum[t] : 0;
    sm[t] = v;
    __syncthreads();
    for (int off = 1; off < 1024; off <<= 1) {
        int u = (t >= off) ? sm[t - off] : 0;
        __syncthreads();
        sm[t] += u;
        __syncthreads();
    }
    if (t < nB) blockpre[t] = sm[t] - v;
    if (t == 1023) outtot[nN] = sm[1023];
}

__global__ __launch_bounds__(256) void csr_scanfinal_kernel(
    const int* __restrict__ cnt, const int* __restrict__ blockpre,
    int* __restrict__ out, int nN)
{
    int b = blockIdx.x, t = threadIdx.x;
    int base = b * 1024 + t * 4;
    int c[4]; int s = 0;
    #pragma unroll
    for (int k = 0; k < 4; ++k) { int i = base + k; c[k] = (i < nN) ? cnt[i] : 0; s += c[k]; }
    int lane = t & 63, w = t >> 6;
    int inc = s;
    #pragma unroll
    for (int off = 1; off < 64; off <<= 1) {
        int u = __shfl_up(inc, off);
        if (lane >= off) inc += u;
    }
    __shared__ int ws[4];
    if (lane == 63) ws[w] = inc;
    __syncthreads();
    int wpre = 0;
    for (int i = 0; i < w; ++i) wpre += ws[i];
    int run = blockpre[b] + wpre + (inc - s);
    #pragma unroll
    for (int k = 0; k < 4; ++k) {
        int i = base + k;
        if (i < nN) { out[i] = run; run += c[k]; }
    }
}

__global__ __launch_bounds__(256) void binscatter_kernel(
    const int* __restrict__ src, const int* __restrict__ dst,
    const int* __restrict__ blkbase, uint32* __restrict__ packed,
    int nE, int nChunks, int nBins)
{
    __shared__ int h[MAXBINS];
    int blk = blockIdx.x, t = threadIdx.x;
    for (int i = t; i < nBins; i += 256) h[i] = 0;
    __syncthreads();
    int e0 = blk * CHUNK;
    int e1 = e0 + CHUNK; if (e1 > nE) e1 = nE;
    for (int e = e0 + t; e < e1; e += 256) {
        int d = dst[e];
        int b = d >> 8;
        int r = atomicAdd(&h[b], 1);        // LDS atomic rank
        int pos = blkbase[(size_t)b * nChunks + blk] + r;
        packed[pos] = (uint32)src[e] | ((uint32)(d & 255) << 24);
    }
}

__global__ __launch_bounds__(256) void binsort_kernel(
    const uint32* __restrict__ packed, const int* __restrict__ blkbase,
    int* __restrict__ rowptr, int* __restrict__ sorted_src,
    int nChunks, int nBins, int nN, int nE)
{
    __shared__ int h[256];
    __shared__ int offs[256];
    __shared__ int ws[4];
    int b = blockIdx.x, t = threadIdx.x;
    int segbase = blkbase[(size_t)b * nChunks];
    int segend  = (b + 1 < nBins) ? blkbase[(size_t)(b + 1) * nChunks] : nE;

    h[t] = 0;
    __syncthreads();
    for (int i = segbase + t; i < segend; i += 256)
        atomicAdd(&h[packed[i] >> 24], 1);
    __syncthreads();

    int c = h[t];
    int lane = t & 63, w = t >> 6;
    int inc = c;
    #pragma unroll
    for (int off = 1; off < 64; off <<= 1) {
        int u = __shfl_up(inc, off);
        if (lane >= off) inc += u;
    }
    if (lane == 63) ws[w] = inc;
    __syncthreads();
    int wpre = 0;
    for (int i = 0; i < w; ++i) wpre += ws[i];
    int ex = wpre + inc - c;
    offs[t] = ex;
    int node = b * 256 + t;
    if (node < nN) rowptr[node] = segbase + ex;
    if (b == 0 && t == 0) rowptr[nN] = nE;
    __syncthreads();

    for (int i = segbase + t; i < segend; i += 256) {
        uint32 pk = packed[i];
        int ld = (int)(pk >> 24);
        int r = atomicAdd(&offs[ld], 1);    // LDS atomic rank
        sorted_src[segbase + r] = (int)(pk & 0x00FFFFFFu);
    }
}

// ---------------- conversions (fused: x->fp8 + weight prep) ----------------
__global__ __launch_bounds__(256) void prep_all_kernel(
    const float4* __restrict__ xin, uint32* __restrict__ xf8out, int n4,
    const float* __restrict__ W1_rel, const float* __restrict__ W1_root,
    const float* __restrict__ W2_rel, const float* __restrict__ W2_root,
    unsigned short* __restrict__ W1relB, unsigned short* __restrict__ W1rootB,
    unsigned short* __restrict__ Wpq)
{
    if (blockIdx.x < 168) {
        int i = blockIdx.x * 256 + threadIdx.x;
        if (i < 16384) {
            W1relB[i] = tobf(W1_rel[i]);
        } else if (i < 32768) {
            int j = i - 16384;
            W1rootB[j] = tobf(W1_root[j]);
        } else if (i < 32768 + 10240) {
            int j = i - 32768;
            int o = j >> 7, k = j & 127;
            float v = (o < 40) ? W2_rel[o * 128 + k] : W2_root[(o - 40) * 128 + k];
            Wpq[j] = tobf(v);
        }
    } else {
        int i = (blockIdx.x - 168) * 256 + threadIdx.x;
        int stride = (gridDim.x - 168) * 256;
        for (; i < n4; i += stride) {
            float4 v = xin[i];
            int w = __builtin_amdgcn_cvt_pk_fp8_f32(v.x, v.y, 0, false);
            w = __builtin_amdgcn_cvt_pk_fp8_f32(v.z, v.w, w, true);
            xf8out[i] = (uint32)w;
        }
    }
}

// ---------------- layer-1 gather (fp8 in, bf16 out, f32 accum) ----------------
// wave = 1 node; half-wave per edge (interleaved); 16-edge main loop + flat
// predicated tail. (R15 configuration — measured fastest.)
__global__ __launch_bounds__(256) void aggregate_fp8_kernel(
    const uint32* __restrict__ xf8u,      // [N][32] uints (128 fp8/row)
    const int* __restrict__ rowptr,
    const int* __restrict__ sorted_src,
    uint2* __restrict__ aggout2,          // [N][32] uint2 (128 bf16/row)
    int nN)
{
    int wave = threadIdx.x >> 6;
    int lane = threadIdx.x & 63;
    int node = blockIdx.x * 4 + wave;
    if (node >= nN) return;
    int half = lane >> 5, l32 = lane & 31;
    int beg = rowptr[node], end = rowptr[node + 1];
    float a0 = 0.f, a1 = 0.f, a2 = 0.f, a3 = 0.f;
    int j = beg;
    for (; j + 16 <= end; j += 16) {
        uint32 u0 = xf8u[(size_t)sorted_src[j + half] * 32 + l32];
        uint32 u1 = xf8u[(size_t)sorted_src[j + 2 + half] * 32 + l32];
        uint32 u2 = xf8u[(size_t)sorted_src[j + 4 + half] * 32 + l32];
        uint32 u3 = xf8u[(size_t)sorted_src[j + 6 + half] * 32 + l32];
        uint32 u4 = xf8u[(size_t)sorted_src[j + 8 + half] * 32 + l32];
        uint32 u5 = xf8u[(size_t)sorted_src[j + 10 + half] * 32 + l32];
        uint32 u6 = xf8u[(size_t)sorted_src[j + 12 + half] * 32 + l32];
        uint32 u7 = xf8u[(size_t)sorted_src[j + 14 + half] * 32 + l32];
        f32x2 p0 = __builtin_amdgcn_cvt_pk_f32_fp8(u0, false);
        f32x2 q0 = __builtin_amdgcn_cvt_pk_f32_fp8(u0, true);
        f32x2 p1 = __builtin_amdgcn_cvt_pk_f32_fp8(u1, false);
        f32x2 q1 = __builtin_amdgcn_cvt_pk_f32_fp8(u1, true);
        f32x2 p2 = __builtin_amdgcn_cvt_pk_f32_fp8(u2, false);
        f32x2 q2 = __builtin_amdgcn_cvt_pk_f32_fp8(u2, true);
        f32x2 p3 = __builtin_amdgcn_cvt_pk_f32_fp8(u3, false);
        f32x2 q3 = __builtin_amdgcn_cvt_pk_f32_fp8(u3, true);
        f32x2 p4 = __builtin_amdgcn_cvt_pk_f32_fp8(u4, false);
        f32x2 q4 = __builtin_amdgcn_cvt_pk_f32_fp8(u4, true);
        f32x2 p5 = __builtin_amdgcn_cvt_pk_f32_fp8(u5, false);
        f32x2 q5 = __builtin_amdgcn_cvt_pk_f32_fp8(u5, true);
        f32x2 p6 = __builtin_amdgcn_cvt_pk_f32_fp8(u6, false);
        f32x2 q6 = __builtin_amdgcn_cvt_pk_f32_fp8(u6, true);
        f32x2 p7 = __builtin_amdgcn_cvt_pk_f32_fp8(u7, false);
        f32x2 q7 = __builtin_amdgcn_cvt_pk_f32_fp8(u7, true);
        a0 += ((p0[0] + p1[0]) + (p2[0] + p3[0])) + ((p4[0] + p5[0]) + (p6[0] + p7[0]));
        a1 += ((p0[1] + p1[1]) + (p2[1] + p3[1])) + ((p4[1] + p5[1]) + (p6[1] + p7[1]));
        a2 += ((q0[0] + q1[0]) + (q2[0] + q3[0])) + ((q4[0] + q5[0]) + (q6[0] + q7[0]));
        a3 += ((q0[1] + q1[1]) + (q2[1] + q3[1])) + ((q4[1] + q5[1]) + (q6[1] + q7[1]));
    }
    // flat predicated tail: remainder < 16 edges, one parallel load round
    {
        uint32 u[8] = {0, 0, 0, 0, 0, 0, 0, 0};
        #pragma unroll
        for (int k = 0; k < 8; ++k) {
            int e = j + 2 * k + half;
            if (e < end) u[k] = xf8u[(size_t)sorted_src[e] * 32 + l32];
        }
        #pragma unroll
        for (int k = 0; k < 8; ++k) {
            f32x2 p = __builtin_amdgcn_cvt_pk_f32_fp8(u[k], false);
            f32x2 q = __builtin_amdgcn_cvt_pk_f32_fp8(u[k], true);
            a0 += p[0]; a1 += p[1]; a2 += q[0]; a3 += q[1];
        }
    }
    a0 += __shfl_xor(a0, 32);
    a1 += __shfl_xor(a1, 32);
    a2 += __shfl_xor(a2, 32);
    a3 += __shfl_xor(a3, 32);
    if (half == 0) {
        uint2 o;
        o.x = (uint32)tobf(a0) | ((uint32)tobf(a1) << 16);
        o.y = (uint32)tobf(a2) | ((uint32)tobf(a3) << 16);
        aggout2[(size_t)node * 32 + l32] = o;
    }
}

// ---------------- fused: h = relu([agg|x]@W1^T + b1); pq = h @ Wpq^T ----------------
__global__ __launch_bounds__(256) void gemm_fused_kernel(
    const unsigned short* __restrict__ aggb,
    const float* __restrict__ xf,
    const unsigned short* __restrict__ Wrel,
    const unsigned short* __restrict__ Wroot,
    const unsigned short* __restrict__ Wpq,    // [80][128]
    const float* __restrict__ b1,
    unsigned char* __restrict__ pf8,           // [N][40] fp8 (+pad)
    unsigned short* __restrict__ qb,           // [N][40] bf16
    int nN)
{
    __shared__ __align__(16) unsigned char lds[32768];    // weight staging
    __shared__ __align__(16) unsigned char hlds[16384];   // h tile 64x128 bf16 (swizzled)
    int tid = threadIdx.x;
    int wave = tid >> 6, lane = tid & 63;
    int i0 = blockIdx.x * 64 + wave * 16;
    int mrow = lane & 15, kslot = lane >> 4;
    int arow = i0 + mrow; if (arow >= nN) arow = 0;

    f32x4 acc[8] = {};
    const unsigned short* Wsrc[2] = {Wrel, Wroot};

    for (int ph = 0; ph < 2; ++ph) {
        __syncthreads();
        const uint4* src = (const uint4*)Wsrc[ph];
        for (int c = tid; c < 2048; c += 256) {
            int row = c >> 4;
            int off = (c & 15) << 4;
            *(uint4*)(&lds[row * 256 + (off ^ ((row & 7) << 4))]) = src[c];
        }
        __syncthreads();
        if (ph == 0) {
            const unsigned short* Ap = aggb + (size_t)arow * 128 + kslot * 8;
            #pragma unroll
            for (int t = 0; t < 4; ++t) {
                bf16x8 a = *(const bf16x8*)(Ap + t * 32);
                #pragma unroll
                for (int ct = 0; ct < 8; ++ct) {
                    int o = ct * 16 + mrow;
                    int off = (t * 64 + kslot * 16) ^ ((o & 7) << 4);
                    bf16x8 b = *(const bf16x8*)(&lds[o * 256 + off]);
                    acc[ct] = __builtin_amdgcn_mfma_f32_16x16x32_bf16(a, b, acc[ct], 0, 0, 0);
                }
            }
        } else {
            const float* Ap = xf + (size_t)arow * 128 + kslot * 8;
            #pragma unroll
            for (int t = 0; t < 4; ++t) {
                float4 f0 = *(const float4*)(Ap + t * 32);
                float4 f1 = *(const float4*)(Ap + t * 32 + 4);
                union { bf16x8 v; unsigned short u[8]; } a;
                a.u[0] = tobf(f0.x); a.u[1] = tobf(f0.y);
                a.u[2] = tobf(f0.z); a.u[3] = tobf(f0.w);
                a.u[4] = tobf(f1.x); a.u[5] = tobf(f1.y);
                a.u[6] = tobf(f1.z); a.u[7] = tobf(f1.w);
                #pragma unroll
                for (int ct = 0; ct < 8; ++ct) {
                    int o = ct * 16 + mrow;
                    int off = (t * 64 + kslot * 16) ^ ((o & 7) << 4);
                    bf16x8 b = *(const bf16x8*)(&lds[o * 256 + off]);
                    acc[ct] = __builtin_amdgcn_mfma_f32_16x16x32_bf16(a.v, b, acc[ct], 0, 0, 0);
                }
            }
        }
    }

    // epilogue 1: bias + relu -> swizzled LDS h tile
    #pragma unroll
    for (int ct = 0; ct < 8; ++ct) {
        int col = ct * 16 + mrow;
        float bias = b1[col];
        #pragma unroll
        for (int r = 0; r < 4; ++r) {
            int rl = wave * 16 + kslot * 4 + r;
            float v = fmaxf(acc[ct][r] + bias, 0.f);
            *(unsigned short*)(&hlds[rl * 256 + ((col * 2) ^ ((rl & 7) << 4))]) = tobf(v);
        }
    }
    __syncthreads();

    // stage Wpq (80 rows x 256B)
    {
        const uint4* src = (const uint4*)Wpq;
        for (int c = tid; c < 1280; c += 256) {
            int row = c >> 4;
            int off = (c & 15) << 4;
            *(uint4*)(&lds[row * 256 + (off ^ ((row & 7) << 4))]) = src[c];
        }
    }
    __syncthreads();

    // pass 2: pq = h @ Wpq^T (5 col-tiles of 16 = 80 cols)
    f32x4 acc2[5] = {};
    {
        int rl = wave * 16 + mrow;
        #pragma unroll
        for (int t = 0; t < 4; ++t) {
            bf16x8 a = *(const bf16x8*)(&hlds[rl * 256 + ((t * 64 + kslot * 16) ^ ((rl & 7) << 4))]);
            #pragma unroll
            for (int ct = 0; ct < 5; ++ct) {
                int o = ct * 16 + mrow;
                int off = (t * 64 + kslot * 16) ^ ((o & 7) << 4);
                bf16x8 b = *(const bf16x8*)(&lds[o * 256 + off]);
                acc2[ct] = __builtin_amdgcn_mfma_f32_16x16x32_bf16(a, b, acc2[ct], 0, 0, 0);
            }
        }
    }

    // epilogue 2: p (cols 0..39) -> fp8 @ stride 40, q (cols 40..79) -> bf16 @ stride 40
    #pragma unroll
    for (int ct = 0; ct < 5; ++ct) {
        int col = ct * 16 + mrow;
        #pragma unroll
        for (int r = 0; r < 4; ++r) {
            int row = i0 + kslot * 4 + r;
            if (row < nN) {
                if (col < 40) pf8[(size_t)row * 40 + col] = tofp8(acc2[ct][r]);
                else          qb[(size_t)row * 40 + (col - 40)] = tobf(acc2[ct][r]);
            }
        }
    }
}

// ---------------- final: out = lsm(gather-sum p[neighbors] + q[node] + b2) ----------------
// wave = 1 node; 3 edges per row-load instruction; 9-edge main loop + flat tail.
// Lanes 60..63 idle. (R15 configuration — measured fastest.)
__global__ __launch_bounds__(256) void final_lsm_kernel(
    const unsigned short* __restrict__ pf8u,  // [N] rows of 20 ushorts (40 fp8)
    const uint32* __restrict__ qbu,           // [N] rows of 20 uints (40 bf16)
    const int* __restrict__ rowptr,
    const int* __restrict__ sorted_src,
    const float* __restrict__ b2,
    float* __restrict__ out,
    int nN)
{
    int wave = threadIdx.x >> 6;
    int lane = threadIdx.x & 63;
    int node = blockIdx.x * 4 + wave;
    if (node >= nN) return;

    int esub = (lane >= 40) ? 2 : (lane >= 20 ? 1 : 0);
    int cp   = lane - esub * 20;
    bool active = lane < 60;
    int beg = rowptr[node], end = rowptr[node + 1];

    // hoist independent node-local loads (overlap with gather)
    uint32 uq = 0;
    float2 bb = make_float2(0.f, 0.f);
    if (lane < 20) {
        uq = qbu[(size_t)node * 20 + lane];
        bb = *(const float2*)(b2 + 2 * lane);
    }

    float a0 = 0.f, a1 = 0.f;
    int j = beg;
    if (active) {
        for (; j + 9 <= end; j += 9) {
            int s0 = sorted_src[j + esub];
            int s1 = sorted_src[j + 3 + esub];
            int s2 = sorted_src[j + 6 + esub];
            uint32 u0 = pf8u[(size_t)s0 * 20 + cp];
            uint32 u1 = pf8u[(size_t)s1 * 20 + cp];
            uint32 u2 = pf8u[(size_t)s2 * 20 + cp];
            f32x2 p0 = __builtin_amdgcn_cvt_pk_f32_fp8(u0, false);
            f32x2 p1 = __builtin_amdgcn_cvt_pk_f32_fp8(u1, false);
            f32x2 p2 = __builtin_amdgcn_cvt_pk_f32_fp8(u2, false);
            a0 += (p0[0] + p1[0]) + p2[0];
            a1 += (p0[1] + p1[1]) + p2[1];
        }
        // flat predicated tail: remainder < 9 edges, one parallel load round
        int e0 = j + esub, e1 = j + 3 + esub, e2 = j + 6 + esub;
        uint32 u0 = 0, u1 = 0, u2 = 0;
        if (e0 < end) u0 = pf8u[(size_t)sorted_src[e0] * 20 + cp];
        if (e1 < end) u1 = pf8u[(size_t)sorted_src[e1] * 20 + cp];
        if (e2 < end) u2 = pf8u[(size_t)sorted_src[e2] * 20 + cp];
        f32x2 p0 = __builtin_amdgcn_cvt_pk_f32_fp8(u0, false);
        f32x2 p1 = __builtin_amdgcn_cvt_pk_f32_fp8(u1, false);
        f32x2 p2 = __builtin_amdgcn_cvt_pk_f32_fp8(u2, false);
        a0 += (p0[0] + p1[0]) + p2[0];
        a1 += (p0[1] + p1[1]) + p2[1];
    }
    // combine the 3 edge-groups: lanes cp, cp+20, cp+40 hold the same class pair
    {
        float t0 = __shfl(a0, cp + 20), t1 = __shfl(a0, cp + 40);
        float t2 = __shfl(a1, cp + 20), t3 = __shfl(a1, cp + 40);
        a0 += t0 + t1;
        a1 += t2 + t3;
    }

    float v0, v1;
    if (lane < 20) {
        v0 = a0 + bflo(uq) + bb.x;
        v1 = a1 + bfhi(uq) + bb.y;
    } else {
        v0 = v1 = -INFINITY;
    }

    // 5-round reduces (values live in lanes 0..19)
    float m = fmaxf(v0, v1);
    #pragma unroll
    for (int off = 16; off >= 1; off >>= 1) m = fmaxf(m, __shfl_xor(m, off));
    float s = (lane < 20) ? (expf(v0 - m) + expf(v1 - m)) : 0.f;
    #pragma unroll
    for (int off = 16; off >= 1; off >>= 1) s += __shfl_xor(s, off);
    float lse = m + logf(s);

    if (lane < 20) {
        float2 o = make_float2(v0 - lse, v1 - lse);
        *(float2*)(out + (size_t)node * 40 + 2 * lane) = o;
    }
}

// ---------------- launch ----------------

static inline char* alignup(char* p, size_t a) {
    return (char*)(((uintptr_t)p + a - 1) & ~(uintptr_t)(a - 1));
}

extern "C" void kernel_launch(void* const* d_in, const int* in_sizes, int n_in,
                              void* d_out, int out_size, void* d_ws, size_t ws_size,
                              hipStream_t stream)
{
    const float* x       = (const float*)d_in[0];
    const int*   ei      = (const int*)d_in[1];
    const float* W1_rel  = (const float*)d_in[2];
    const float* b1      = (const float*)d_in[3];
    const float* W1_root = (const float*)d_in[4];
    const float* W2_rel  = (const float*)d_in[5];
    const float* b2      = (const float*)d_in[6];
    const float* W2_root = (const float*)d_in[7];

    int N = in_sizes[0] / 128;
    int E = in_sizes[1] / 2;
    const int* srcp = ei;
    const int* dstp = ei + E;

    int nChunks = (E + CHUNK - 1) / CHUNK;          // 391
    int nBins   = (N + 255) >> 8;                   // 391
    int nScan   = nBins * nChunks;                  // ~153k
    int nB2     = (nScan + 1023) / 1024;
    size_t nf = (size_t)N * 128;

    char* p = (char*)d_ws;
    unsigned char*  xf8     = (unsigned char*)p;   p += nf;            // [N][128] fp8
    unsigned short* aggb    = (unsigned short*)p;  p += nf * 2;        // [N][128] bf16
    p = alignup(p, 16);
    unsigned char*  pf8     = (unsigned char*)p;   p += (size_t)N * 40 + 64; // [N][40] fp8 + pad
    p = alignup(p, 16);
    unsigned short* qb      = (unsigned short*)p;  p += (size_t)N * 40 * 2;  // [N][40] bf16
    p = alignup(p, 16);
    unsigned short* W1relB  = (unsigned short*)p;  p += 16384 * 2;
    unsigned short* W1rootB = (unsigned short*)p;  p += 16384 * 2;
    unsigned short* Wpq     = (unsigned short*)p;  p += 10240 * 2;
    p = alignup(p, 16);
    int* rowptr     = (int*)p;  p += (size_t)(N + 1) * 4;
    p = alignup(p, 16);
    int* blkhist    = (int*)p;  p += (size_t)nScan * 4;
    int* blkbase    = (int*)p;  p += (size_t)(nScan + 1) * 4;
    int* blocksum   = (int*)p;  p += (size_t)nB2 * 4;
    int* blockpre   = (int*)p;  p += (size_t)nB2 * 4;
    p = alignup(p, 16);
    uint32* packed  = (uint32*)p; p += (size_t)E * 4;
    p = alignup(p, 16);
    int* sorted_src = (int*)p;  p += (size_t)E * 4;

    if ((size_t)(p - (char*)d_ws) > ws_size || nBins > MAXBINS) return;

    // CSR build: 2-level counting sort, all atomics in LDS
    binhist_kernel<<<nChunks, 256, 0, stream>>>(dstp, blkhist, E, nChunks, nBins);
    csr_partial_kernel<<<nB2, 256, 0, stream>>>(blkhist, blocksum, nScan);
    csr_scanblocks_kernel<<<1, 1024, 0, stream>>>(blocksum, blockpre, nB2, blkbase, nScan);
    csr_scanfinal_kernel<<<nB2, 256, 0, stream>>>(blkhist, blockpre, blkbase, nScan);
    binscatter_kernel<<<nChunks, 256, 0, stream>>>(srcp, dstp, blkbase, packed, E, nChunks, nBins);
    binsort_kernel<<<nBins, 256, 0, stream>>>(packed, blkbase, rowptr, sorted_src,
                                              nChunks, nBins, N, E);

    // fused conversions: weights (blocks 0..167) + x->fp8 (blocks 168..)
    prep_all_kernel<<<168 + 2048, 256, 0, stream>>>(
        (const float4*)x, (uint32*)xf8, (int)(nf / 4),
        W1_rel, W1_root, W2_rel, W2_root, W1relB, W1rootB, Wpq);

    // layer 1 gather
    aggregate_fp8_kernel<<<(N + 3) / 4, 256, 0, stream>>>(
        (const uint32*)xf8, rowptr, sorted_src, (uint2*)aggb, N);

    // fused layer-1 GEMM + layer-2 pre-transform
    gemm_fused_kernel<<<(N + 63) / 64, 256, 0, stream>>>(
        aggb, x, W1relB, W1rootB, Wpq, b1, pf8, qb, N);

    // fused gather + log-softmax
    final_lsm_kernel<<<(N + 3) / 4, 256, 0, stream>>>(
        (const unsigned short*)pf8, (const uint32*)qb, rowptr, sorted_src,
        b2, (float*)d_out, N);
}